// Round 1
// baseline (212.660 us; speedup 1.0000x reference)
//
#include <hip/hip_runtime.h>

#define NEG (-1e30f)

// Problem dims (fixed by setup_inputs): B=16, TXT=128, MEL=512, NM=80
#define B_   16
#define TXT_ 128
#define MEL_ 512
#define NM_  80

// ---------------------------------------------------------------------------
// Kernel 1: log_prob_matrix.
//   lp[b,i,t] = -0.5/80 * ( sum_n (x[b,t,n]-mu[b,i,n])^2 * exp(-lv[b,i,n])
//                           + sum_n lv[b,i,n] )
// One block per (b,i); thread t covers one mel frame. Also emits transposed
// lpT[b,t,i] into workspace for coalesced scan reads, and zero-inits out[0]
// (the scan kernels atomicAdd into it afterwards; stream order guarantees
// the zero lands first).
// ---------------------------------------------------------------------------
__global__ __launch_bounds__(512) void lp_kernel(
    const float* __restrict__ mu_logvar,  // (B, TXT, 2*NM)
    const float* __restrict__ melspec,    // (B, NM, MEL)
    float* __restrict__ lp_out,           // (B, TXT, MEL)  = d_out + 1
    float* __restrict__ lpT,              // (B, MEL, TXT)  in ws, or null
    float* __restrict__ out0)             // d_out[0]
{
    const int i = blockIdx.x;   // 0..127
    const int b = blockIdx.y;   // 0..15
    const int t = threadIdx.x;  // 0..511

    __shared__ float2 s_muw[NM_];   // (mu, exp(-lv))
    __shared__ float  s_lv[NM_];
    __shared__ float  s_c0;

    const float* row = mu_logvar + (size_t)(b * TXT_ + i) * (2 * NM_);
    if (t < NM_) {
        float mu = row[t];
        float lv = row[NM_ + t];
        s_muw[t] = make_float2(mu, __expf(-lv));
        s_lv[t]  = lv;
    }
    __syncthreads();
    if (t == 0) {
        float c = 0.f;
        #pragma unroll
        for (int n = 0; n < NM_; ++n) c += s_lv[n];
        s_c0 = c;
    }
    __syncthreads();

    // x[b,t,n] = melspec[b, n, t]; lane-contiguous in t -> coalesced.
    const float* xcol = melspec + (size_t)b * NM_ * MEL_ + t;
    float acc = 0.f;
    #pragma unroll 8
    for (int n = 0; n < NM_; ++n) {
        float x  = xcol[(size_t)n * MEL_];
        float2 mw = s_muw[n];
        float d  = x - mw.x;
        acc = fmaf(d * d, mw.y, acc);
    }
    float res = (-0.5f / (float)NM_) * (acc + s_c0);

    lp_out[((size_t)(b * TXT_ + i)) * MEL_ + t] = res;
    if (lpT) lpT[((size_t)(b * MEL_ + t)) * TXT_ + i] = res;

    if (b == 0 && i == 0 && t == 0) *out0 = 0.f;
}

// ---------------------------------------------------------------------------
// Kernel 2: monotonic-alignment forward scan, one wave (64 lanes) per batch.
// Lane l holds alpha[l] (lo) and alpha[l+64] (hi); neighbor shift entirely
// in-register via shuffles -> zero barriers on the 511-step serial chain.
// Parametric strides let us read either lpT (t_str=TXT, j_str=1, coalesced)
// or raw lp (t_str=1, j_str=MEL) if the workspace is too small.
// ---------------------------------------------------------------------------
__device__ __forceinline__ float logaddexp_(float a, float b) {
    float m  = fmaxf(a, b);
    float mn = fminf(a, b);
    return m + __logf(1.f + __expf(mn - m));
}

__global__ __launch_bounds__(64) void scan_kernel(
    const float* __restrict__ lp, int t_str, int j_str,
    const int* __restrict__ text_len, const int* __restrict__ mel_len,
    float* __restrict__ out0)
{
    const int b    = blockIdx.x;
    const int lane = threadIdx.x;
    const float* base = lp + (size_t)b * TXT_ * MEL_;

    const int Tend = mel_len[b];           // process t = 1 .. Tend-1

    // init (t=0): only j==0 gets lp[b,0,0]
    float alpha_lo = (lane == 0) ? base[0] : NEG;
    float alpha_hi = NEG;

    const int off_lo = lane * j_str;
    const int off_hi = (lane + 64) * j_str;

    // 2-deep register prefetch of lp rows (mel_len >= 256 so t=1,2 exist)
    float pl0 = base[1 * t_str + off_lo];
    float ph0 = base[1 * t_str + off_hi];
    float pl1 = base[2 * t_str + off_lo];
    float ph1 = base[2 * t_str + off_hi];

    for (int t = 1; t < Tend; ++t) {
        float lp_lo = pl0, lp_hi = ph0;
        pl0 = pl1; ph0 = ph1;
        int tp = t + 2;
        if (tp < Tend) {
            pl1 = base[(size_t)tp * t_str + off_lo];
            ph1 = base[(size_t)tp * t_str + off_hi];
        }

        // shifted[j] = alpha[j-1]; j=0 -> NEG; j=64 -> alpha[63] (lo lane 63)
        float from63 = __shfl(alpha_lo, 63);
        float sh_lo  = __shfl_up(alpha_lo, 1);
        float sh_hi  = __shfl_up(alpha_hi, 1);
        if (lane == 0) { sh_lo = NEG; sh_hi = from63; }

        alpha_lo = logaddexp_(alpha_lo, sh_lo) + lp_lo;
        alpha_hi = logaddexp_(alpha_hi, sh_hi) + lp_hi;
    }

    int jstar = text_len[b] - 1;
    float val = (jstar < 64) ? __shfl(alpha_lo, jstar)
                             : __shfl(alpha_hi, jstar - 64);
    if (lane == 0) {
        atomicAdd(out0, -(val / (float)Tend) * (1.f / (float)B_));
    }
}

// ---------------------------------------------------------------------------
extern "C" void kernel_launch(void* const* d_in, const int* in_sizes, int n_in,
                              void* d_out, int out_size, void* d_ws, size_t ws_size,
                              hipStream_t stream) {
    const float* mu_logvar = (const float*)d_in[0];
    const float* melspec   = (const float*)d_in[1];
    const int*   text_len  = (const int*)d_in[2];
    const int*   mel_len   = (const int*)d_in[3];

    float* out    = (float*)d_out;      // out[0] = mdn_loss, out[1..] = lp
    float* lp_out = out + 1;

    const size_t lpT_bytes = (size_t)B_ * MEL_ * TXT_ * sizeof(float);
    float* lpT = (ws_size >= lpT_bytes) ? (float*)d_ws : nullptr;

    dim3 g1(TXT_, B_);
    lp_kernel<<<g1, MEL_, 0, stream>>>(mu_logvar, melspec, lp_out, lpT, out);

    if (lpT) {
        scan_kernel<<<B_, 64, 0, stream>>>(lpT, TXT_, 1, text_len, mel_len, out);
    } else {
        scan_kernel<<<B_, 64, 0, stream>>>(lp_out, 1, MEL_, text_len, mel_len, out);
    }
}

// Round 3
// 172.710 us; speedup vs baseline: 1.2313x; 1.2313x over previous
//
#include <hip/hip_runtime.h>

#define NEG (-1e30f)

// Problem dims (fixed by setup_inputs): B=16, TXT=128, MEL=512, NM=80
#define B_   16
#define TXT_ 128
#define MEL_ 512
#define NM_  80
#define IT_  8     // i-rows per lp block

// ---------------------------------------------------------------------------
// Kernel 1: log_prob_matrix, 8 i-rows per block, coalesced-only stores.
//   (x-mu)^2 * w + lv  ==  w*x^2 + b*x + c,  w=exp(-lv), b=-2*mu*w,
//   c = mu^2*w + lv  (c summed over n once per i).
// Each thread owns one mel frame t; each melspec load feeds 8 i-rows.
// NOTE: IT_*NM_ = 640 > blockDim 512 -> the LDS fill MUST be a strided loop
// (R2's single-shot `if (t < 640)` left ii=6/7 garbage and failed the bench).
// ---------------------------------------------------------------------------
__global__ __launch_bounds__(512) void lp_kernel(
    const float* __restrict__ mu_logvar,  // (B, TXT, 2*NM)
    const float* __restrict__ melspec,    // (B, NM, MEL)
    float* __restrict__ lp_out,           // (B, TXT, MEL)  = d_out + 1
    float* __restrict__ out0)             // d_out[0]
{
    const int i0 = blockIdx.x * IT_;   // 0,8,...,120
    const int b  = blockIdx.y;
    const int t  = threadIdx.x;        // 0..511

    __shared__ float2 s_wb[IT_][NM_];     // (w, b) per (i,n)
    __shared__ float  s_cp[IT_ * NM_];    // per-(i,n) c, reduced below
    __shared__ float  s_cc[IT_];          // per-i sum of c

    for (int u = t; u < IT_ * NM_; u += 512) {
        int ii = u / NM_;
        int n  = u - ii * NM_;
        const float* row = mu_logvar + (size_t)(b * TXT_ + i0 + ii) * (2 * NM_);
        float mu = row[n];
        float lv = row[NM_ + n];
        float w  = __expf(-lv);
        s_wb[ii][n] = make_float2(w, -2.f * mu * w);
        s_cp[u]     = mu * mu * w + lv;
    }
    __syncthreads();
    if (t < IT_) {
        float c = 0.f;
        #pragma unroll
        for (int n = 0; n < NM_; ++n) c += s_cp[t * NM_ + n];
        s_cc[t] = c;
    }
    __syncthreads();

    const float* xcol = melspec + (size_t)b * NM_ * MEL_ + t;
    float acc[IT_];
    #pragma unroll
    for (int ii = 0; ii < IT_; ++ii) acc[ii] = 0.f;

    #pragma unroll 4
    for (int n = 0; n < NM_; ++n) {
        float x  = xcol[(size_t)n * MEL_];
        float x2 = x * x;
        #pragma unroll
        for (int ii = 0; ii < IT_; ++ii) {
            float2 wb = s_wb[ii][n];
            acc[ii] = fmaf(wb.x, x2, fmaf(wb.y, x, acc[ii]));
        }
    }

    float* dst = lp_out + ((size_t)(b * TXT_ + i0)) * MEL_ + t;
    #pragma unroll
    for (int ii = 0; ii < IT_; ++ii) {
        dst[(size_t)ii * MEL_] = (-0.5f / (float)NM_) * (acc[ii] + s_cc[ii]);
    }

    if (i0 == 0 && b == 0 && t == 0) *out0 = 0.f;
}

// ---------------------------------------------------------------------------
// Kernel 2: LDS-tiled transpose lp(B,TXT,MEL) -> lpT(B,MEL,TXT).
// Coalesced reads AND writes; 32x33 tile kills bank conflicts.
// ---------------------------------------------------------------------------
__global__ __launch_bounds__(256) void transpose_kernel(
    const float* __restrict__ lp, float* __restrict__ lpT)
{
    __shared__ float tile[32][33];
    const int t0 = blockIdx.x * 32;   // mel tile
    const int i0 = blockIdx.y * 32;   // txt tile
    const int b  = blockIdx.z;
    const int tx = threadIdx.x;       // 0..31
    const int ty = threadIdx.y;       // 0..7

    const float* src = lp + ((size_t)(b * TXT_ + i0)) * MEL_ + t0;
    #pragma unroll
    for (int r = 0; r < 32; r += 8)
        tile[ty + r][tx] = src[(size_t)(ty + r) * MEL_ + tx];  // [i_loc][t_loc]
    __syncthreads();

    float* dst = lpT + ((size_t)(b * MEL_ + t0)) * TXT_ + i0;
    #pragma unroll
    for (int r = 0; r < 32; r += 8)
        dst[(size_t)(ty + r) * TXT_ + tx] = tile[tx][ty + r];
}

// ---------------------------------------------------------------------------
// Kernel 3: monotonic-alignment forward scan, one wave per batch.
// Lane l holds alpha[l] / alpha[l+64]; 8-deep register prefetch ring (16
// loads in flight) hides L2/L3 latency; unrolled x8 so slots stay static.
// ---------------------------------------------------------------------------
__device__ __forceinline__ float logaddexp_(float a, float b) {
    float m  = fmaxf(a, b);
    float mn = fminf(a, b);
    return m + __logf(1.f + __expf(mn - m));
}

#define PF_ 8

__global__ __launch_bounds__(64) void scan_kernel(
    const float* __restrict__ lp, int t_str, int j_str,
    const int* __restrict__ text_len, const int* __restrict__ mel_len,
    float* __restrict__ out0)
{
    const int b    = blockIdx.x;
    const int lane = threadIdx.x;
    const float* base = lp + (size_t)b * TXT_ * MEL_;

    const int Tend = mel_len[b];   // steps t = 1 .. Tend-1 ; Tend >= 256

    float alpha_lo = (lane == 0) ? base[0] : NEG;
    float alpha_hi = NEG;

    const int off_lo = lane * j_str;
    const int off_hi = (lane + 64) * j_str;

    float pl[PF_], ph[PF_];
    #pragma unroll
    for (int s = 0; s < PF_; ++s) {
        int tt = min(1 + s, Tend - 1);
        pl[s] = base[(size_t)tt * t_str + off_lo];
        ph[s] = base[(size_t)tt * t_str + off_hi];
    }

    int t = 1;
    #define STEP(LPLO, LPHI)                                         \
        do {                                                         \
            float from63 = __shfl(alpha_lo, 63);                     \
            float sh_lo  = __shfl_up(alpha_lo, 1);                   \
            float sh_hi  = __shfl_up(alpha_hi, 1);                   \
            if (lane == 0) { sh_lo = NEG; sh_hi = from63; }          \
            alpha_lo = logaddexp_(alpha_lo, sh_lo) + (LPLO);         \
            alpha_hi = logaddexp_(alpha_hi, sh_hi) + (LPHI);         \
        } while (0)

    while (t <= Tend - PF_) {
        #pragma unroll
        for (int s = 0; s < PF_; ++s) {
            STEP(pl[s], ph[s]);
            int tp = min(t + s + PF_, Tend - 1);
            pl[s] = base[(size_t)tp * t_str + off_lo];
            ph[s] = base[(size_t)tp * t_str + off_hi];
        }
        t += PF_;
    }
    #pragma unroll
    for (int s = 0; s < PF_; ++s) {
        if (t + s < Tend) STEP(pl[s], ph[s]);
    }
    #undef STEP

    int jstar = text_len[b] - 1;
    float val = (jstar < 64) ? __shfl(alpha_lo, jstar)
                             : __shfl(alpha_hi, jstar - 64);
    if (lane == 0) {
        atomicAdd(out0, -(val / (float)Tend) * (1.f / (float)B_));
    }
}

// ---------------------------------------------------------------------------
extern "C" void kernel_launch(void* const* d_in, const int* in_sizes, int n_in,
                              void* d_out, int out_size, void* d_ws, size_t ws_size,
                              hipStream_t stream) {
    const float* mu_logvar = (const float*)d_in[0];
    const float* melspec   = (const float*)d_in[1];
    const int*   text_len  = (const int*)d_in[2];
    const int*   mel_len   = (const int*)d_in[3];

    float* out    = (float*)d_out;      // out[0] = mdn_loss, out[1..] = lp
    float* lp_out = out + 1;

    const size_t lpT_bytes = (size_t)B_ * MEL_ * TXT_ * sizeof(float);
    float* lpT = (ws_size >= lpT_bytes) ? (float*)d_ws : nullptr;

    dim3 g1(TXT_ / IT_, B_);
    lp_kernel<<<g1, MEL_, 0, stream>>>(mu_logvar, melspec, lp_out, out);

    if (lpT) {
        dim3 g2(MEL_ / 32, TXT_ / 32, B_);
        transpose_kernel<<<g2, dim3(32, 8), 0, stream>>>(lp_out, lpT);
        scan_kernel<<<B_, 64, 0, stream>>>(lpT, TXT_, 1, text_len, mel_len, out);
    } else {
        scan_kernel<<<B_, 64, 0, stream>>>(lp_out, 1, MEL_, text_len, mel_len, out);
    }
}

// Round 4
// 156.360 us; speedup vs baseline: 1.3601x; 1.1046x over previous
//
#include <hip/hip_runtime.h>

#define NEG (-1e30f)

// Problem dims (fixed by setup_inputs): B=16, TXT=128, MEL=512, NM=80
#define B_   16
#define TXT_ 128
#define MEL_ 512
#define NM_  80
#define IT_  8     // i-rows per lp block

// ---------------------------------------------------------------------------
// Kernel 1: log_prob_matrix, 8 i-rows per block, coalesced-only stores.
//   (x-mu)^2 * w + lv  ==  w*x^2 + b*x + c,  w=exp(-lv), b=-2*mu*w,
//   c = mu^2*w + lv  (c summed over n once per i).
// Writes lp twice: to d_out+1 (output, only 4B-aligned) and to d_ws (16B-
// aligned copy the scan can float4-load).
// NOTE: IT_*NM_ = 640 > blockDim 512 -> LDS fill must be a strided loop.
// ---------------------------------------------------------------------------
__global__ __launch_bounds__(512) void lp_kernel(
    const float* __restrict__ mu_logvar,  // (B, TXT, 2*NM)
    const float* __restrict__ melspec,    // (B, NM, MEL)
    float* __restrict__ lp_out,           // (B, TXT, MEL)  = d_out + 1
    float* __restrict__ lp_ws,            // (B, TXT, MEL)  aligned copy in ws
    float* __restrict__ out0)             // d_out[0]
{
    const int i0 = blockIdx.x * IT_;   // 0,8,...,120
    const int b  = blockIdx.y;
    const int t  = threadIdx.x;        // 0..511

    __shared__ float2 s_wb[IT_][NM_];     // (w, b) per (i,n)
    __shared__ float  s_cp[IT_ * NM_];    // per-(i,n) c, reduced below
    __shared__ float  s_cc[IT_];          // per-i sum of c

    for (int u = t; u < IT_ * NM_; u += 512) {
        int ii = u / NM_;
        int n  = u - ii * NM_;
        const float* row = mu_logvar + (size_t)(b * TXT_ + i0 + ii) * (2 * NM_);
        float mu = row[n];
        float lv = row[NM_ + n];
        float w  = __expf(-lv);
        s_wb[ii][n] = make_float2(w, -2.f * mu * w);
        s_cp[u]     = mu * mu * w + lv;
    }
    __syncthreads();
    if (t < IT_) {
        float c = 0.f;
        #pragma unroll
        for (int n = 0; n < NM_; ++n) c += s_cp[t * NM_ + n];
        s_cc[t] = c;
    }
    __syncthreads();

    const float* xcol = melspec + (size_t)b * NM_ * MEL_ + t;
    float acc[IT_];
    #pragma unroll
    for (int ii = 0; ii < IT_; ++ii) acc[ii] = 0.f;

    #pragma unroll 4
    for (int n = 0; n < NM_; ++n) {
        float x  = xcol[(size_t)n * MEL_];
        float x2 = x * x;
        #pragma unroll
        for (int ii = 0; ii < IT_; ++ii) {
            float2 wb = s_wb[ii][n];
            acc[ii] = fmaf(wb.x, x2, fmaf(wb.y, x, acc[ii]));
        }
    }

    const size_t rowbase = ((size_t)(b * TXT_ + i0)) * MEL_ + t;
    #pragma unroll
    for (int ii = 0; ii < IT_; ++ii) {
        float res = (-0.5f / (float)NM_) * (acc[ii] + s_cc[ii]);
        lp_out[rowbase + (size_t)ii * MEL_] = res;
        lp_ws [rowbase + (size_t)ii * MEL_] = res;
    }

    if (i0 == 0 && b == 0 && t == 0) *out0 = 0.f;
}

// ---------------------------------------------------------------------------
// Kernel 2: skewed-systolic monotonic-alignment scan. One wave per batch.
// Lane l owns columns j0=2l, j1=2l+1 and computes step t = d - 4*l at
// iteration d. Boundary alpha[t-1][2l-1] is lane l-1's a1-state shuffled
// 4 iterations earlier (4-entry register delay ring r[]) -> ds_bpermute
// latency is OFF the critical path. lp loads are per-lane float4 streams
// (skew 4 keeps every lane's t congruent mod 4 -> uniform component index),
// triple-buffered with ~8 iterations of lead.
// Pre-start lanes (t<1) self-absorb: -1e30 + anything stays -1e30 in fp32.
// Post-end corruption is harmless: lane l+1 only ever consumes lane l's
// states for steps <= Tend-2 (the skew makes consumers strictly lag
// producers); each lane snapshots its own result at t == Tend-1.
// ---------------------------------------------------------------------------
__device__ __forceinline__ float laexp(float a, float b) {
    float m = fmaxf(a, b);
    float d = fminf(a, b) - m;               // <= 0; exp underflows safely
    return m + __logf(1.f + __expf(d));
}
__device__ __forceinline__ float getc(const float4& v, int c) {
    switch (c & 3) { case 0: return v.x; case 1: return v.y;
                     case 2: return v.z; default: return v.w; }
}

__global__ __launch_bounds__(64) void scan_kernel(
    const float* __restrict__ lp,          // aligned copy (B, TXT, MEL)
    const int* __restrict__ text_len, const int* __restrict__ mel_len,
    float* __restrict__ out0)
{
    const int b = blockIdx.x;
    const int l = threadIdx.x;
    const float* base = lp + (size_t)b * TXT_ * MEL_;
    const int Tend = mel_len[b], TendM1 = Tend - 1;   // Tend in [256,512]

    const float* row0 = base + (size_t)(2 * l) * MEL_;   // j0 row (16B aligned)

    float lp00 = base[0];
    float a0 = (l == 0) ? lp00 : NEG;   // alpha[0][j0]
    float a1 = NEG;                     // alpha[0][j1]
    float fin0 = NEG, fin1 = NEG;

    int t_cur = 1 - 4 * l;              // t at d=1
    int t_pf  = 12 - 4 * l;             // next prefetch block start

    float4 q0[3], q1[3];                // triple-buffered lp rows j0/j1
    #pragma unroll
    for (int s = 0; s < 3; ++s) {
        int tc = min(max(4 * s - 4 * l, 0), MEL_ - 4);
        q0[s] = *(const float4*)(row0 + tc);
        q1[s] = *(const float4*)(row0 + MEL_ + tc);
    }
    float r[4] = {NEG, NEG, NEG, NEG};  // boundary delay ring (depth 4)

    const int D = TendM1 + 4 * 63;      // lane 63 finishes t=TendM1 here
    for (int d0 = 1; d0 <= D; d0 += 12) {
        #pragma unroll
        for (int k = 0; k < 12; ++k) {
            const int slot = ((k + 1) >> 2) % 3;   // folds under unroll
            const int cmp_ = (k + 1) & 3;
            // consume boundary shuffled 4 iterations ago, then refill slot
            float bnd = (l == 0) ? NEG : r[cmp_];  // r index == d&3 == cmp_
            r[cmp_] = __shfl_up(a1, 1);            // state at start of iter
            float lpv0 = getc(q0[slot], cmp_);
            float lpv1 = getc(q1[slot], cmp_);
            float na0 = laexp(a0, bnd) + lpv0;     // alpha[t][j0]
            float na1 = laexp(a1, a0)  + lpv1;     // alpha[t][j1]
            bool hit = (t_cur == TendM1);
            fin0 = hit ? na0 : fin0;
            fin1 = hit ? na1 : fin1;
            a0 = na0; a1 = na1;
            ++t_cur;
            if (cmp_ == 3) {                       // k = 2,6,10: refill slot
                int tc = min(max(t_pf, 0), MEL_ - 4);
                q0[slot] = *(const float4*)(row0 + tc);
                q1[slot] = *(const float4*)(row0 + MEL_ + tc);
                t_pf += 4;
            }
        }
    }

    int jstar = text_len[b] - 1;                   // in [63,127]
    float v   = (jstar & 1) ? fin1 : fin0;
    float val = __shfl(v, jstar >> 1);
    if (l == 0) atomicAdd(out0, -(val / (float)Tend) * (1.f / (float)B_));
}

// ---------------------------------------------------------------------------
extern "C" void kernel_launch(void* const* d_in, const int* in_sizes, int n_in,
                              void* d_out, int out_size, void* d_ws, size_t ws_size,
                              hipStream_t stream) {
    const float* mu_logvar = (const float*)d_in[0];
    const float* melspec   = (const float*)d_in[1];
    const int*   text_len  = (const int*)d_in[2];
    const int*   mel_len   = (const int*)d_in[3];

    float* out    = (float*)d_out;      // out[0] = mdn_loss, out[1..] = lp
    float* lp_out = out + 1;
    float* lp_ws  = (float*)d_ws;       // 16B-aligned lp copy (4 MB)

    dim3 g1(TXT_ / IT_, B_);
    lp_kernel<<<g1, MEL_, 0, stream>>>(mu_logvar, melspec, lp_out, lp_ws, out);
    scan_kernel<<<B_, 64, 0, stream>>>(lp_ws, text_len, mel_len, out);
}